// Round 4
// baseline (246.764 us; speedup 1.0000x reference)
//
#include <hip/hip_runtime.h>
#include <math.h>

// Spherical harmonics edge attributes, lmax=2.
// Outputs (concat flat): edge_vec [E,3] | edge_length [E] | edge_sh [E,9]
//
// Strategy: 1 edge/thread, 256 threads/block.
//  - gathers read pos [N,3] DIRECTLY (1.2 MB -> L2-resident; dwordx3 loads).
//    No d_ws packing kernel: the kernel is a pure function of its inputs,
//    so graph replays / fresh launches are deterministic by construction.
//  - shift staged through LDS with coalesced non-temporal float4 loads
//  - outputs staged in LDS, flushed with coalesced NON-TEMPORAL float4 stores
//    (nt keeps the streaming traffic from evicting pos out of L2)
//  - the idx->gather dependent-load chain is issued BEFORE the shift
//    staging + barrier, so its ~1000cy latency overlaps the staging phase
//    instead of sitting on the post-barrier critical path.
//  - edge_length written directly with per-lane nt scalar stores
//    (stride-4 across the wave = one fully-covered 256B chunk) - no LDS hop.
//
// Note: __builtin_nontemporal_* requires native vector types, not HIP's
// float4 class -> use ext_vector_type(4) float (v4f) for those accesses.

#define SQRT3 1.7320508075688772f
#define SQRT5 2.2360679774997896f

typedef float v4f __attribute__((ext_vector_type(4)));

__global__ __launch_bounds__(256) void sh_edge_kernel(
    const float*  __restrict__ pos,       // [N,3]
    const int*    __restrict__ edge_index,// [2,E]
    const float*  __restrict__ shift,     // [E,3]
    float* __restrict__ out_vec,          // [E,3]
    float* __restrict__ out_len,          // [E]
    float* __restrict__ out_sh,           // [E,9]
    int n_edges)
{
    __shared__ float s_shift[768];   // 256 edges x 3
    __shared__ float s_vec[768];     // 256 x 3
    __shared__ float s_sh[2304];     // 256 x 9

    const int tid  = threadIdx.x;
    const int base = blockIdx.x * 256;
    const int nblk = min(256, n_edges - base);   // edges in this block
    const bool full = (nblk == 256);

    // ---- phase 0: issue the latency-critical loads FIRST ----
    // idx (nt, streamed) -> pos gather (L2-resident). This dependent chain
    // is the longest latency in the kernel; issuing it here lets it overlap
    // the shift staging and the barrier below. All operands are pure INPUT
    // buffers — no workspace state, no inter-kernel ordering.
    float psx = 0.f, psy = 0.f, psz = 0.f, pdx = 0.f, pdy = 0.f, pdz = 0.f;
    if (tid < nblk) {
        const int e = base + tid;
        const int s = __builtin_nontemporal_load(&edge_index[e]);
        const int d = __builtin_nontemporal_load(&edge_index[n_edges + e]);
        const float* ps = pos + 3 * (size_t)s;
        const float* pd = pos + 3 * (size_t)d;
        psx = ps[0]; psy = ps[1]; psz = ps[2];
        pdx = pd[0]; pdy = pd[1]; pdz = pd[2];
    }

    // ---- phase 1: stage shift (coalesced, non-temporal: single-use stream) ----
    if (full) {
        const v4f* g = reinterpret_cast<const v4f*>(shift + 3 * (size_t)base);
        if (tid < 192) {
            v4f v = __builtin_nontemporal_load(&g[tid]);
            reinterpret_cast<v4f*>(s_shift)[tid] = v;
        }
    } else {
        for (int i = tid; i < 3 * nblk; i += 256)
            s_shift[i] = shift[3 * (size_t)base + i];
    }
    __syncthreads();

    // ---- phase 2: compute (gather results arrive here via vmcnt wait) ----
    if (tid < nblk) {
        const int e = base + tid;

        float x = pdx - psx - s_shift[3 * tid + 0];
        float y = pdy - psy - s_shift[3 * tid + 1];
        float z = pdz - psz - s_shift[3 * tid + 2];

        s_vec[3 * tid + 0] = x;
        s_vec[3 * tid + 1] = y;
        s_vec[3 * tid + 2] = z;

        float sq = x * x + y * y + z * z;
        float r  = rsqrtf(sq);
        // edge_length: stride-4 per-lane store = fully covered 256B/wave,
        // write directly (non-temporal), no LDS round trip needed.
        __builtin_nontemporal_store(sq * r, &out_len[e]);

        float nx = x * r, ny = y * r, nz = z * r;
        float x2 = nx * nx, y2 = ny * ny, z2 = nz * nz;

        float* o = s_sh + 9 * tid;
        o[0] = 1.0f;
        o[1] = SQRT3 * nx;
        o[2] = SQRT3 * ny;
        o[3] = SQRT3 * nz;
        o[4] = SQRT5 * SQRT3 * nx * nz;
        o[5] = SQRT5 * SQRT3 * nx * ny;
        o[6] = SQRT5 * (y2 - 0.5f * (x2 + z2));
        o[7] = SQRT5 * SQRT3 * ny * nz;
        o[8] = SQRT5 * 0.5f * SQRT3 * (z2 - x2);
    }
    __syncthreads();

    // ---- phase 3: flush outputs (coalesced non-temporal float4) ----
    if (full) {
        v4f* gv = reinterpret_cast<v4f*>(out_vec + 3 * (size_t)base);
        const v4f* lv = reinterpret_cast<const v4f*>(s_vec);
        if (tid < 192) __builtin_nontemporal_store(lv[tid], &gv[tid]);

        v4f* gs = reinterpret_cast<v4f*>(out_sh + 9 * (size_t)base);
        const v4f* ls = reinterpret_cast<const v4f*>(s_sh);
        __builtin_nontemporal_store(ls[tid],       &gs[tid]);
        __builtin_nontemporal_store(ls[256 + tid], &gs[256 + tid]);
        if (tid < 64) __builtin_nontemporal_store(ls[512 + tid], &gs[512 + tid]);
    } else {
        for (int i = tid; i < 3 * nblk; i += 256) out_vec[3 * (size_t)base + i] = s_vec[i];
        for (int i = tid; i < 9 * nblk; i += 256) out_sh[9 * (size_t)base + i]  = s_sh[i];
    }
}

extern "C" void kernel_launch(void* const* d_in, const int* in_sizes, int n_in,
                              void* d_out, int out_size, void* d_ws, size_t ws_size,
                              hipStream_t stream) {
    const float* pos        = (const float*)d_in[0];
    const int*   edge_index = (const int*)d_in[1];
    const float* shift      = (const float*)d_in[2];

    const int n_edges = in_sizes[2] / 3;   // shift is [E,3]

    float* out_vec = (float*)d_out;                        // [E,3]
    float* out_len = (float*)d_out + 3 * (size_t)n_edges;  // [E]
    float* out_sh  = (float*)d_out + 4 * (size_t)n_edges;  // [E,9]

    const int blocks = (n_edges + 255) / 256;
    sh_edge_kernel<<<blocks, 256, 0, stream>>>(
        pos, edge_index, shift, out_vec, out_len, out_sh, n_edges);
}

// Round 5
// 244.444 us; speedup vs baseline: 1.0095x; 1.0095x over previous
//
#include <hip/hip_runtime.h>
#include <math.h>

// Spherical harmonics edge attributes, lmax=2.
// Outputs (concat flat): edge_vec [E,3] | edge_length [E] | edge_sh [E,9]
//
// Strategy: 2 edges/thread, 256 threads/block (512 edges/block).
//  - pure function of input buffers (no d_ws): deterministic by construction.
//  - issue order per block: idx loads -> shift staging loads -> pos gathers
//    -> LDS-write staging. The staging ds_write waits only its own loads
//    (vmcnt leaves the gathers in flight); gather latency hides under the
//    staging + barrier and is first waited in the compute phase.
//  - shift staged through LDS with coalesced non-temporal float4 loads.
//  - outputs staged in LDS, flushed with coalesced NON-TEMPORAL float4 stores
//    (nt keeps streaming traffic from evicting pos out of L2).
//  - edge_length written directly with per-lane nt scalar stores
//    (stride-4 across the wave = fully-covered 256B chunks) - no LDS hop.
//
// Note: __builtin_nontemporal_* requires native vector types, not HIP's
// float4 class -> use ext_vector_type(4) float (v4f) for those accesses.

#define SQRT3 1.7320508075688772f
#define SQRT5 2.2360679774997896f

typedef float v4f __attribute__((ext_vector_type(4)));

__global__ __launch_bounds__(256) void sh_edge_kernel(
    const float*  __restrict__ pos,       // [N,3]
    const int*    __restrict__ edge_index,// [2,E]
    const float*  __restrict__ shift,     // [E,3]
    float* __restrict__ out_vec,          // [E,3]
    float* __restrict__ out_len,          // [E]
    float* __restrict__ out_sh,           // [E,9]
    int n_edges)
{
    __shared__ float s_shift[1536];   // 512 edges x 3
    __shared__ float s_vec[1536];     // 512 x 3
    __shared__ float s_sh[4608];      // 512 x 9

    const int tid  = threadIdx.x;
    const int base = blockIdx.x * 512;
    const int rem  = n_edges - base;

    if (rem >= 512) {
        // ================= full block: 2 edges/thread =================
        const int e0 = base + tid;
        const int e1 = e0 + 256;

        // (1) idx loads FIRST (oldest outstanding) - coalesced nt dwords.
        const int s0 = __builtin_nontemporal_load(&edge_index[e0]);
        const int s1 = __builtin_nontemporal_load(&edge_index[e1]);
        const int d0 = __builtin_nontemporal_load(&edge_index[n_edges + e0]);
        const int d1 = __builtin_nontemporal_load(&edge_index[n_edges + e1]);

        // (2) shift staging loads into registers (issued before gathers so the
        //     later ds_write can wait on these without draining the gathers).
        v4f r0 = {0.f, 0.f, 0.f, 0.f}, r1 = {0.f, 0.f, 0.f, 0.f};
        const v4f* g = reinterpret_cast<const v4f*>(shift + 3 * (size_t)base);
        if (tid < 192) {                  // 384 v4f = 1536 floats
            r0 = __builtin_nontemporal_load(&g[tid]);
            r1 = __builtin_nontemporal_load(&g[tid + 192]);
        }

        // (3) gathers (dependent on idx; compiler waits only the idx loads).
        const float* ps0 = pos + 3 * (size_t)s0;
        const float* pd0 = pos + 3 * (size_t)d0;
        const float* ps1 = pos + 3 * (size_t)s1;
        const float* pd1 = pos + 3 * (size_t)d1;
        const float ax0 = ps0[0], ay0 = ps0[1], az0 = ps0[2];
        const float bx0 = pd0[0], by0 = pd0[1], bz0 = pd0[2];
        const float ax1 = ps1[0], ay1 = ps1[1], az1 = ps1[2];
        const float bx1 = pd1[0], by1 = pd1[1], bz1 = pd1[2];

        // (4) stage shift to LDS (waits staging loads; gathers stay in flight)
        if (tid < 192) {
            reinterpret_cast<v4f*>(s_shift)[tid]       = r0;
            reinterpret_cast<v4f*>(s_shift)[tid + 192] = r1;
        }
        __syncthreads();

        // (5) compute both edges
#define EDGE_COMPUTE(k, X, Y, Z)                                         \
        {                                                                \
            const float x = (X), y = (Y), z = (Z);                       \
            s_vec[3*(k)+0] = x; s_vec[3*(k)+1] = y; s_vec[3*(k)+2] = z;  \
            const float sq = x*x + y*y + z*z;                            \
            const float r  = rsqrtf(sq);                                 \
            __builtin_nontemporal_store(sq * r, &out_len[base + (k)]);   \
            const float nx = x*r, ny = y*r, nz = z*r;                    \
            const float x2 = nx*nx, y2 = ny*ny, z2 = nz*nz;              \
            float* o = s_sh + 9*(k);                                     \
            o[0] = 1.0f;                                                 \
            o[1] = SQRT3 * nx;                                           \
            o[2] = SQRT3 * ny;                                           \
            o[3] = SQRT3 * nz;                                           \
            o[4] = SQRT5 * SQRT3 * nx * nz;                              \
            o[5] = SQRT5 * SQRT3 * nx * ny;                              \
            o[6] = SQRT5 * (y2 - 0.5f * (x2 + z2));                      \
            o[7] = SQRT5 * SQRT3 * ny * nz;                              \
            o[8] = SQRT5 * 0.5f * SQRT3 * (z2 - x2);                     \
        }

        EDGE_COMPUTE(tid,
                     bx0 - ax0 - s_shift[3*tid + 0],
                     by0 - ay0 - s_shift[3*tid + 1],
                     bz0 - az0 - s_shift[3*tid + 2]);
        EDGE_COMPUTE(tid + 256,
                     bx1 - ax1 - s_shift[3*(tid+256) + 0],
                     by1 - ay1 - s_shift[3*(tid+256) + 1],
                     bz1 - az1 - s_shift[3*(tid+256) + 2]);
#undef EDGE_COMPUTE
        __syncthreads();

        // (6) flush outputs (coalesced non-temporal float4)
        v4f* gv = reinterpret_cast<v4f*>(out_vec + 3 * (size_t)base);
        const v4f* lv = reinterpret_cast<const v4f*>(s_vec);
        if (tid < 192) {
            __builtin_nontemporal_store(lv[tid],       &gv[tid]);
            __builtin_nontemporal_store(lv[tid + 192], &gv[tid + 192]);
        }

        v4f* gs = reinterpret_cast<v4f*>(out_sh + 9 * (size_t)base);
        const v4f* ls = reinterpret_cast<const v4f*>(s_sh);   // 1152 v4f
        __builtin_nontemporal_store(ls[tid],        &gs[tid]);
        __builtin_nontemporal_store(ls[tid + 256],  &gs[tid + 256]);
        __builtin_nontemporal_store(ls[tid + 512],  &gs[tid + 512]);
        __builtin_nontemporal_store(ls[tid + 768],  &gs[tid + 768]);
        if (tid < 128)
            __builtin_nontemporal_store(ls[tid + 1024], &gs[tid + 1024]);
    } else {
        // ================= tail block: scalar fallback =================
        // (rem is block-uniform, so skipping the barriers above is safe)
        for (int k = tid; k < rem; k += 256) {
            const int e = base + k;
            const int s = edge_index[e];
            const int d = edge_index[n_edges + e];
            const float x = pos[3*(size_t)d + 0] - pos[3*(size_t)s + 0] - shift[3*(size_t)e + 0];
            const float y = pos[3*(size_t)d + 1] - pos[3*(size_t)s + 1] - shift[3*(size_t)e + 1];
            const float z = pos[3*(size_t)d + 2] - pos[3*(size_t)s + 2] - shift[3*(size_t)e + 2];
            out_vec[3*(size_t)e + 0] = x;
            out_vec[3*(size_t)e + 1] = y;
            out_vec[3*(size_t)e + 2] = z;
            const float sq = x*x + y*y + z*z;
            const float r  = rsqrtf(sq);
            out_len[e] = sq * r;
            const float nx = x*r, ny = y*r, nz = z*r;
            const float x2 = nx*nx, y2 = ny*ny, z2 = nz*nz;
            float* o = out_sh + 9*(size_t)e;
            o[0] = 1.0f;
            o[1] = SQRT3 * nx;
            o[2] = SQRT3 * ny;
            o[3] = SQRT3 * nz;
            o[4] = SQRT5 * SQRT3 * nx * nz;
            o[5] = SQRT5 * SQRT3 * nx * ny;
            o[6] = SQRT5 * (y2 - 0.5f * (x2 + z2));
            o[7] = SQRT5 * SQRT3 * ny * nz;
            o[8] = SQRT5 * 0.5f * SQRT3 * (z2 - x2);
        }
    }
}

extern "C" void kernel_launch(void* const* d_in, const int* in_sizes, int n_in,
                              void* d_out, int out_size, void* d_ws, size_t ws_size,
                              hipStream_t stream) {
    const float* pos        = (const float*)d_in[0];
    const int*   edge_index = (const int*)d_in[1];
    const float* shift      = (const float*)d_in[2];

    const int n_edges = in_sizes[2] / 3;   // shift is [E,3]

    float* out_vec = (float*)d_out;                        // [E,3]
    float* out_len = (float*)d_out + 3 * (size_t)n_edges;  // [E]
    float* out_sh  = (float*)d_out + 4 * (size_t)n_edges;  // [E,9]

    const int blocks = (n_edges + 511) / 512;
    sh_edge_kernel<<<blocks, 256, 0, stream>>>(
        pos, edge_index, shift, out_vec, out_len, out_sh, n_edges);
}